// Round 8
// baseline (195.902 us; speedup 1.0000x reference)
//
#include <hip/hip_runtime.h>

// ---------------------------------------------------------------------------
// DiscriminatorMBD, fp32 end-to-end except GEMM (bf16x3 MFMA, ~1e-6 rel err):
//  kP: prep — conv1 weights c1ws[w4][tap25][8]; conv2 weights ws2[w4][ic20]
//      [tap25][12] (wave-uniform scalar-load layouts); T -> bf16 hi/lo
//  kC: fused conv1+pool + conv2+pool, 1 image/block. Wave-uniform weights via
//      s_load (scalar pipe); LDS carries only img + h1. 2 barriers total.
//  k3m: M = feats @ T^T via mfma_f32_16x16x32_bf16 (x3 split), no LDS
//  k4: partial closeness over j-quarters -> cp[16][512][64]
//  k5: concat + fc1 + relu + fc2 + sigmoid -> out[512]
// ---------------------------------------------------------------------------

typedef __attribute__((ext_vector_type(8))) short bf16x8;
typedef __attribute__((ext_vector_type(4))) float f32x4;

static __device__ __forceinline__ unsigned short f2bf(float x) {
  unsigned int u = __float_as_uint(x);
  unsigned int r = (u + 0x7fffu + ((u >> 16) & 1u)) >> 16;
  return (unsigned short)r;
}
static __device__ __forceinline__ float bf2f(unsigned short h) {
  return __uint_as_float(((unsigned int)h) << 16);
}

// ---- kP: weight transforms + T bf16 split ---------------------------------
__global__ __launch_bounds__(256) void kP_prep(
    const float* __restrict__ c1w, const float* __restrict__ c2w,
    const float* __restrict__ T, float* __restrict__ ws2,
    float* __restrict__ c1ws, unsigned short* __restrict__ Th,
    unsigned short* __restrict__ Tl) {
  const int idx = blockIdx.x * 256 + threadIdx.x;
  if (idx < 655360) {
    const float v = T[idx];
    const unsigned short h = f2bf(v);
    Th[idx] = h;
    Tl[idx] = f2bf(v - bf2f(h));
  }
  if (idx < 24000) {  // ws2[w][ic][tap][12]: oc = w*10 + sl (sl<10)
    const int w = idx / 6000;
    const int r = idx - w * 6000;
    const int ic = r / 300;
    const int r2 = r - ic * 300;
    const int tap = r2 / 12;
    const int sl = r2 - tap * 12;
    float val = 0.f;
    if (sl < 10) val = c2w[(w * 10 + sl) * 500 + ic * 25 + tap];
    ws2[idx] = val;
  }
  if (idx < 800) {  // c1ws[w][tap][8]: ch = w*5 + c (c<5)
    const int w = idx / 200;
    const int r = idx - w * 200;
    const int tap = r >> 3;
    const int c = r & 7;
    float val = 0.f;
    if (c < 5) val = c1w[(w * 5 + c) * 25 + tap];
    c1ws[idx] = val;
  }
}

// ---- kC: fused conv1+pool -> conv2+pool, wave-uniform weights -------------
// 512 blocks x 256 thr (4 waves). Wave w: conv1 chs w*5..w*5+4, conv2 ocs
// w*10..w*10+9. Lane: conv1 = pooled pos (3 passes over 144); conv2 = conv
// position (cy,cx) in 8x8. Weights via uniform scalar loads.
__global__ __launch_bounds__(256) void kC_conv(
    const float* __restrict__ x, const float* __restrict__ c1ws,
    const float* __restrict__ c1b, const float* __restrict__ ws2,
    const float* __restrict__ c2b, float* __restrict__ feats,
    unsigned short* __restrict__ fh, unsigned short* __restrict__ fl) {
  __shared__ __align__(16) float img[784];
  __shared__ __align__(16) float h1s[2880];

  const int tid = threadIdx.x;
  const int imgId = blockIdx.x;
  const int wid = __builtin_amdgcn_readfirstlane(tid >> 6);
  const int l = tid & 63;

  {  // stage image
    float4* dst = reinterpret_cast<float4*>(img);
    const float4* src = reinterpret_cast<const float4*>(x + imgId * 784);
    for (int t = tid; t < 196; t += 256) dst[t] = src[t];
  }
  __syncthreads();

  // ---- conv1: 144 pooled positions per wave-chgroup, 3 passes ----
  const float* __restrict__ w1b = c1ws + wid * 200;
#pragma unroll 1
  for (int pi = 0; pi < 3; ++pi) {
    const int posidx = pi * 64 + l;
    if (posidx < 144) {
      const int py = posidx / 12;
      const int px = posidx - py * 12;
      float pv[6][6];
      const float* ib = &img[py * 2 * 28 + px * 2];
#pragma unroll
      for (int r = 0; r < 6; ++r) {
        const float2 a = *reinterpret_cast<const float2*>(&ib[r * 28 + 0]);
        const float2 b = *reinterpret_cast<const float2*>(&ib[r * 28 + 2]);
        const float2 c = *reinterpret_cast<const float2*>(&ib[r * 28 + 4]);
        pv[r][0] = a.x; pv[r][1] = a.y; pv[r][2] = b.x;
        pv[r][3] = b.y; pv[r][4] = c.x; pv[r][5] = c.y;
      }
      float acc[5][4];
#pragma unroll
      for (int c = 0; c < 5; ++c)
#pragma unroll
        for (int u = 0; u < 4; ++u) acc[c][u] = 0.f;
#pragma unroll
      for (int ky = 0; ky < 5; ++ky) {
#pragma unroll
        for (int kx = 0; kx < 5; ++kx) {
          const int tap = ky * 5 + kx;
          const float4 wv = *reinterpret_cast<const float4*>(&w1b[tap * 8]);
          const float w4 = w1b[tap * 8 + 4];
          const float i00 = pv[ky][kx];
          const float i01 = pv[ky][kx + 1];
          const float i10 = pv[ky + 1][kx];
          const float i11 = pv[ky + 1][kx + 1];
          acc[0][0] += i00 * wv.x; acc[0][1] += i01 * wv.x;
          acc[0][2] += i10 * wv.x; acc[0][3] += i11 * wv.x;
          acc[1][0] += i00 * wv.y; acc[1][1] += i01 * wv.y;
          acc[1][2] += i10 * wv.y; acc[1][3] += i11 * wv.y;
          acc[2][0] += i00 * wv.z; acc[2][1] += i01 * wv.z;
          acc[2][2] += i10 * wv.z; acc[2][3] += i11 * wv.z;
          acc[3][0] += i00 * wv.w; acc[3][1] += i01 * wv.w;
          acc[3][2] += i10 * wv.w; acc[3][3] += i11 * wv.w;
          acc[4][0] += i00 * w4; acc[4][1] += i01 * w4;
          acc[4][2] += i10 * w4; acc[4][3] += i11 * w4;
        }
      }
#pragma unroll
      for (int c = 0; c < 5; ++c) {
        const float m =
            fmaxf(fmaxf(acc[c][0], acc[c][1]), fmaxf(acc[c][2], acc[c][3])) +
            c1b[wid * 5 + c];
        h1s[(wid * 5 + c) * 144 + posidx] = fmaxf(m, 0.f);
      }
    }
  }
  __syncthreads();

  // ---- conv2: lane = conv position (cy,cx) in 8x8; 10 oc per wave ----
  const int cy = l >> 3;
  const int cx = l & 7;
  const int s = cx & ~1;
  const bool dsh = (cx & 1) != 0;
  float acc[10];
#pragma unroll
  for (int q = 0; q < 10; ++q) acc[q] = 0.f;

  const float* __restrict__ w2b = ws2 + wid * 6000;
#pragma unroll 1
  for (int ic = 0; ic < 20; ++ic) {
    float pd[5][5];
    {
      const float* ib = &h1s[ic * 144 + cy * 12 + s];
#pragma unroll
      for (int r = 0; r < 5; ++r) {
        const float2 a = *reinterpret_cast<const float2*>(&ib[r * 12 + 0]);
        const float2 b = *reinterpret_cast<const float2*>(&ib[r * 12 + 2]);
        const float2 c = *reinterpret_cast<const float2*>(&ib[r * 12 + 4]);
        pd[r][0] = dsh ? a.y : a.x;
        pd[r][1] = dsh ? b.x : a.y;
        pd[r][2] = dsh ? b.y : b.x;
        pd[r][3] = dsh ? c.x : b.y;
        pd[r][4] = dsh ? c.y : c.x;
      }
    }
    const float* wt = w2b + ic * 300;
#pragma unroll
    for (int ky = 0; ky < 5; ++ky) {
#pragma unroll
      for (int kx = 0; kx < 5; ++kx) {
        const int tap = ky * 5 + kx;
        const float4 w03 = *reinterpret_cast<const float4*>(&wt[tap * 12]);
        const float4 w47 = *reinterpret_cast<const float4*>(&wt[tap * 12 + 4]);
        const float2 w89 = *reinterpret_cast<const float2*>(&wt[tap * 12 + 8]);
        const float iv = pd[ky][kx];
        acc[0] += iv * w03.x; acc[1] += iv * w03.y;
        acc[2] += iv * w03.z; acc[3] += iv * w03.w;
        acc[4] += iv * w47.x; acc[5] += iv * w47.y;
        acc[6] += iv * w47.z; acc[7] += iv * w47.w;
        acc[8] += iv * w89.x; acc[9] += iv * w89.y;
      }
    }
  }

  // ---- 2x2 pool across lanes (cx^1, cy^1), bias, relu, write ----
#pragma unroll
  for (int q = 0; q < 10; ++q) {
    acc[q] = fmaxf(acc[q], __shfl_xor(acc[q], 1));
    acc[q] = fmaxf(acc[q], __shfl_xor(acc[q], 8));
  }
  if ((l & 9) == 0) {  // cy even, cx even
    const int pos = (cy >> 1) * 4 + (cx >> 1);
#pragma unroll
    for (int q = 0; q < 10; ++q) {
      const int ch = wid * 10 + q;
      const float r0v = fmaxf(acc[q] + c2b[ch], 0.f);
      const int off = imgId * 640 + ch * 16 + pos;
      feats[off] = r0v;
      const unsigned short h0 = f2bf(r0v);
      fh[off] = h0;
      fl[off] = f2bf(r0v - bf2f(h0));
    }
  }
}

// ---- k3m: M = feats @ T^T via bf16x3 MFMA, direct-from-global -------------
__global__ __launch_bounds__(256) void k3m_gemm(
    const unsigned short* __restrict__ fh, const unsigned short* __restrict__ fl,
    const unsigned short* __restrict__ Th, const unsigned short* __restrict__ Tl,
    float* __restrict__ M) {
  const int tid = threadIdx.x;
  const int w = tid >> 6;
  const int l = tid & 63;
  const int fr = l & 15;
  const int hi = l >> 4;
  const int if0 = blockIdx.x >> 4;            // 0..31
  const int jf = (blockIdx.x & 15) * 4 + w;   // 0..63
  const int abase = (if0 * 16 + fr) * 640 + hi * 8;
  const int bbase = (jf * 16 + fr) * 640 + hi * 8;

  f32x4 acc = (f32x4){0.f, 0.f, 0.f, 0.f};
#pragma unroll
  for (int kk = 0; kk < 20; ++kk) {
    const int ko = kk * 32;
    const bf16x8 aH = *reinterpret_cast<const bf16x8*>(fh + abase + ko);
    const bf16x8 aL = *reinterpret_cast<const bf16x8*>(fl + abase + ko);
    const bf16x8 bH = *reinterpret_cast<const bf16x8*>(Th + bbase + ko);
    const bf16x8 bL = *reinterpret_cast<const bf16x8*>(Tl + bbase + ko);
    acc = __builtin_amdgcn_mfma_f32_16x16x32_bf16(aH, bH, acc, 0, 0, 0);
    acc = __builtin_amdgcn_mfma_f32_16x16x32_bf16(aL, bH, acc, 0, 0, 0);
    acc = __builtin_amdgcn_mfma_f32_16x16x32_bf16(aH, bL, acc, 0, 0, 0);
  }
#pragma unroll
  for (int r = 0; r < 4; ++r) {
    M[(if0 * 16 + hi * 4 + r) * 1024 + jf * 16 + fr] = acc[r];
  }
}

// ---- k4: partial closeness, LDS-staged swizzled j-rows --------------------
__global__ __launch_bounds__(256) void k4_mbd(const float* __restrict__ M,
                                              float* __restrict__ cp) {
  __shared__ float4 jb4[2][4][256];
  const int bid = blockIdx.x;
  const int ig = bid >> 4;
  const int jq = bid & 15;
  const int t = threadIdx.x;
  const int b = t & 63;
  const int g = t >> 6;
  const int i0 = ig * 16 + g * 4;
  const float4* Mf4 = reinterpret_cast<const float4*>(M);

  float4 mi[4][4];
#pragma unroll
  for (int u = 0; u < 4; ++u) {
#pragma unroll
    for (int q = 0; q < 4; ++q) mi[u][q] = Mf4[(i0 + u) * 256 + b * 4 + q];
  }
  const int wslot = (t >> 2) * 4 + ((t & 3) ^ ((t >> 3) & 3));
  {
#pragma unroll
    for (int k = 0; k < 4; ++k)
      jb4[0][k][wslot] = Mf4[(jq * 32 + k) * 256 + t];
  }
  __syncthreads();

  float acc[4] = {0.f, 0.f, 0.f, 0.f};
  const int xr = (b >> 1) & 3;
  for (int c = 0; c < 8; ++c) {
    float4 st[4];
    if (c < 7) {
#pragma unroll
      for (int k = 0; k < 4; ++k)
        st[k] = Mf4[(jq * 32 + (c + 1) * 4 + k) * 256 + t];
    }
    const int cbuf = c & 1;
#pragma unroll
    for (int jj = 0; jj < 4; ++jj) {
      const float4* rowp = jb4[cbuf][jj];
      float4 mj[4];
#pragma unroll
      for (int q = 0; q < 4; ++q) mj[q] = rowp[b * 4 + (q ^ xr)];
#pragma unroll
      for (int u = 0; u < 4; ++u) {
        float dist =
            fabsf(mi[u][0].x - mj[0].x) + fabsf(mi[u][0].y - mj[0].y) +
            fabsf(mi[u][0].z - mj[0].z) + fabsf(mi[u][0].w - mj[0].w) +
            fabsf(mi[u][1].x - mj[1].x) + fabsf(mi[u][1].y - mj[1].y) +
            fabsf(mi[u][1].z - mj[1].z) + fabsf(mi[u][1].w - mj[1].w) +
            fabsf(mi[u][2].x - mj[2].x) + fabsf(mi[u][2].y - mj[2].y) +
            fabsf(mi[u][2].z - mj[2].z) + fabsf(mi[u][2].w - mj[2].w) +
            fabsf(mi[u][3].x - mj[3].x) + fabsf(mi[u][3].y - mj[3].y) +
            fabsf(mi[u][3].z - mj[3].z) + fabsf(mi[u][3].w - mj[3].w);
        acc[u] += __expf(-dist);
      }
    }
    if (c < 7) {
#pragma unroll
      for (int k = 0; k < 4; ++k) jb4[(c + 1) & 1][k][wslot] = st[k];
    }
    __syncthreads();
  }
#pragma unroll
  for (int u = 0; u < 4; ++u)
    cp[(jq * 512 + i0 + u) * 64 + b] = acc[u];
}

// ---- k5: head -------------------------------------------------------------
__global__ __launch_bounds__(256) void k5_head(
    const float* __restrict__ feats, const float* __restrict__ cp,
    const float* __restrict__ w1, const float* __restrict__ b1,
    const float* __restrict__ w2, const float* __restrict__ b2,
    float* __restrict__ out) {
  __shared__ __align__(16) float v[704];
  __shared__ float hb[100];
  const int i = blockIdx.x;
  const int tid = threadIdx.x;
  float4* v4 = reinterpret_cast<float4*>(v);
  if (tid < 160)
    v4[tid] = reinterpret_cast<const float4*>(feats + i * 640)[tid];
  if (tid >= 192) {
    const int bb = tid - 192;
    float s = 0.f;
#pragma unroll
    for (int q = 0; q < 16; ++q) s += cp[(q * 512 + i) * 64 + bb];
    v[640 + bb] = s;
  }
  __syncthreads();
  const int wave = tid >> 6;
  const int lane = tid & 63;
  for (int r = wave; r < 100; r += 4) {
    const float4* wr = reinterpret_cast<const float4*>(w1 + r * 704);
    const float4 wa = wr[lane];
    const float4 wb = wr[lane + 64];
    const float4 va = v4[lane];
    const float4 vb = v4[lane + 64];
    float s = wa.x * va.x + wa.y * va.y + wa.z * va.z + wa.w * va.w +
              wb.x * vb.x + wb.y * vb.y + wb.z * vb.z + wb.w * vb.w;
    if (lane < 48) {
      const float4 wc = wr[lane + 128];
      const float4 vc = v4[lane + 128];
      s += wc.x * vc.x + wc.y * vc.y + wc.z * vc.z + wc.w * vc.w;
    }
#pragma unroll
    for (int off = 32; off; off >>= 1) s += __shfl_xor(s, off);
    if (lane == 0) hb[r] = fmaxf(s + b1[r], 0.f) * w2[r];
  }
  __syncthreads();
  if (tid < 64) {
    float s = hb[tid] + ((tid < 36) ? hb[tid + 64] : 0.f);
#pragma unroll
    for (int off = 32; off; off >>= 1) s += __shfl_xor(s, off);
    if (tid == 0) out[i] = 1.f / (1.f + __expf(-(s + b2[0])));
  }
}

extern "C" void kernel_launch(void* const* d_in, const int* in_sizes, int n_in,
                              void* d_out, int out_size, void* d_ws,
                              size_t ws_size, hipStream_t stream) {
  const float* x   = (const float*)d_in[0];
  const float* c1w = (const float*)d_in[1];
  const float* c1b = (const float*)d_in[2];
  const float* c2w = (const float*)d_in[3];
  const float* c2b = (const float*)d_in[4];
  const float* T   = (const float*)d_in[5];
  const float* f1w = (const float*)d_in[6];
  const float* f1b = (const float*)d_in[7];
  const float* f2w = (const float*)d_in[8];
  const float* f2b = (const float*)d_in[9];
  float* out = (float*)d_out;

  float* feats = (float*)d_ws;                    // 327680 f
  float* M     = feats + 327680;                  // 524288 f
  float* cp    = M + 524288;                      // 524288 f
  float* ws2   = cp + 524288;                     // 24000 f
  float* c1ws  = ws2 + 24000;                     // 800 f
  unsigned short* fh = (unsigned short*)(c1ws + 800);   // 327680 u16
  unsigned short* fl = fh + 327680;
  unsigned short* Th = fl + 327680;               // 655360 u16
  unsigned short* Tl = Th + 655360;
  // total ~9.5 MB

  kP_prep<<<2560, 256, 0, stream>>>(c1w, c2w, T, ws2, c1ws, Th, Tl);
  kC_conv<<<512, 256, 0, stream>>>(x, c1ws, c1b, ws2, c2b, feats, fh, fl);
  k3m_gemm<<<512, 256, 0, stream>>>(fh, fl, Th, Tl, M);
  k4_mbd<<<512, 256, 0, stream>>>(M, cp);
  k5_head<<<512, 256, 0, stream>>>(feats, cp, f1w, f1b, f2w, f2b, out);
}

// Round 9
// 182.251 us; speedup vs baseline: 1.0749x; 1.0749x over previous
//
#include <hip/hip_runtime.h>

// ---------------------------------------------------------------------------
// DiscriminatorMBD, fp32 end-to-end except GEMM (bf16x3 MFMA, ~1e-6 rel err):
//  kP: prep — conv2 weight transform ws2[ic][tap][slot64]; T -> bf16 hi/lo
//  kC: fused conv1+relu+pool + conv2+relu+pool (1 image/block, 512 blocks),
//      LDS double-buffered weights, packed-fp32 (v_pk_fma) inner loops
//  k3m: M = feats @ T^T via mfma_f32_16x16x32_bf16 (x3 split), no LDS
//  k4: partial closeness over j-quarters -> cp[16][512][64]
//  k5: concat + fc1 + relu + fc2 + sigmoid -> out[512]
// ---------------------------------------------------------------------------

typedef __attribute__((ext_vector_type(8))) short bf16x8;
typedef __attribute__((ext_vector_type(4))) float f32x4;
typedef __attribute__((ext_vector_type(2))) float v2f;

static __device__ __forceinline__ unsigned short f2bf(float x) {
  unsigned int u = __float_as_uint(x);
  unsigned int r = (u + 0x7fffu + ((u >> 16) & 1u)) >> 16;
  return (unsigned short)r;
}
static __device__ __forceinline__ float bf2f(unsigned short h) {
  return __uint_as_float(((unsigned int)h) << 16);
}

// ---- kP: weight transform + T bf16 split ----------------------------------
// ws2 flat: ((ic*25 + tap)*64 + grp*8 + q), oc = grp*5+q (q<5 valid, else 0)
__global__ __launch_bounds__(256) void kP_prep(
    const float* __restrict__ c2w, const float* __restrict__ T,
    float* __restrict__ ws2, unsigned short* __restrict__ Th,
    unsigned short* __restrict__ Tl) {
  const int idx = blockIdx.x * 256 + threadIdx.x;
  if (idx < 655360) {
    const float v = T[idx];
    const unsigned short h = f2bf(v);
    Th[idx] = h;
    Tl[idx] = f2bf(v - bf2f(h));
  }
  if (idx < 32000) {
    const int ic = idx / 1600;
    const int r = idx - ic * 1600;
    const int tap = r >> 6;
    const int slot = r & 63;
    const int grp = slot >> 3;
    const int q = slot & 7;
    float val = 0.f;
    if (q < 5) val = c2w[(grp * 5 + q) * 500 + ic * 25 + tap];
    ws2[idx] = val;
  }
}

// ---- kC: fused conv1+pool -> conv2+pool, 1 image/block --------------------
// 512 blocks x 256 thr. conv1: 720 quads over 256 thr, packed over adjacent
// positions. conv2: thread = (h ic-half, grp of 5 oc, pos of 16), packed over
// oc pairs (weights from aligned float4 LDS reads). Double-buffered weights.
__global__ __launch_bounds__(256) void kC_conv(
    const float* __restrict__ x, const float* __restrict__ c1w,
    const float* __restrict__ c1b, const float* __restrict__ ws2,
    const float* __restrict__ c2b, float* __restrict__ feats,
    unsigned short* __restrict__ fh, unsigned short* __restrict__ fl) {
  __shared__ __align__(16) float img[784];
  __shared__ __align__(16) float h1s[2880];
  __shared__ float wl1[500];
  __shared__ float bl1[20];
  __shared__ float bl2[40];
  __shared__ __align__(16) float wl2[2][2][1600];  // [ic-stream][parity][tap*64+slot]
  __shared__ float mg[128][21];

  const int tid = threadIdx.x;
  const int imgId = blockIdx.x;

  {  // stage image + conv1 weights + biases
    float4* dst = reinterpret_cast<float4*>(img);
    const float4* src = reinterpret_cast<const float4*>(x + imgId * 784);
    for (int t = tid; t < 196; t += 256) dst[t] = src[t];
  }
  for (int t = tid; t < 500; t += 256) wl1[t] = c1w[t];
  if (tid < 20) bl1[tid] = c1b[tid];
  if (tid >= 64 && tid < 104) bl2[tid - 64] = c2b[tid - 64];
  __syncthreads();

  // ---- conv1: 720 quads (ch, 2-row band, 4 pooled outputs), packed pairs --
  for (int qd = tid; qd < 720; qd += 256) {
    const int ch = qd / 36;
    const int rem = qd - ch * 36;
    const int py = rem / 3;
    const int qx = rem - py * 3;
    const int r0 = py * 2;
    const int c0 = qx * 8;
    float p[6][12];
#pragma unroll
    for (int r = 0; r < 6; ++r) {
      const float* ib = &img[(r0 + r) * 28 + c0];
      const float4 a = *reinterpret_cast<const float4*>(ib);
      const float4 b = *reinterpret_cast<const float4*>(ib + 4);
      const float4 c = *reinterpret_cast<const float4*>(ib + 8);
      p[r][0] = a.x; p[r][1] = a.y; p[r][2] = a.z; p[r][3] = a.w;
      p[r][4] = b.x; p[r][5] = b.y; p[r][6] = b.z; p[r][7] = b.w;
      p[r][8] = c.x; p[r][9] = c.y; p[r][10] = c.z; p[r][11] = c.w;
    }
    v2f sp[4][2];  // [quad-output u][dy] = (dx0, dx1)
#pragma unroll
    for (int u = 0; u < 4; ++u)
#pragma unroll
      for (int dy = 0; dy < 2; ++dy) sp[u][dy] = (v2f){0.f, 0.f};
    const float* wc = &wl1[ch * 25];
#pragma unroll
    for (int ky = 0; ky < 5; ++ky) {
#pragma unroll
      for (int kx = 0; kx < 5; ++kx) {
        const float w = wc[ky * 5 + kx];
        const v2f wv = {w, w};
#pragma unroll
        for (int u = 0; u < 4; ++u) {
#pragma unroll
          for (int dy = 0; dy < 2; ++dy) {
            const v2f in = {p[ky + dy][2 * u + kx], p[ky + dy][2 * u + kx + 1]};
            sp[u][dy] += in * wv;
          }
        }
      }
    }
    const float bb = bl1[ch];
    float4 o;
    o.x = fmaxf(fmaxf(fmaxf(sp[0][0].x, sp[0][0].y),
                      fmaxf(sp[0][1].x, sp[0][1].y)) + bb, 0.f);
    o.y = fmaxf(fmaxf(fmaxf(sp[1][0].x, sp[1][0].y),
                      fmaxf(sp[1][1].x, sp[1][1].y)) + bb, 0.f);
    o.z = fmaxf(fmaxf(fmaxf(sp[2][0].x, sp[2][0].y),
                      fmaxf(sp[2][1].x, sp[2][1].y)) + bb, 0.f);
    o.w = fmaxf(fmaxf(fmaxf(sp[3][0].x, sp[3][0].y),
                      fmaxf(sp[3][1].x, sp[3][1].y)) + bb, 0.f);
    *reinterpret_cast<float4*>(&h1s[ch * 144 + py * 12 + qx * 4]) = o;
  }

  // ---- initial conv2 weight stage (parity 0): ic = 0 and ic = 10 ----
  float4* wlf4 = reinterpret_cast<float4*>(&wl2[0][0][0]);
  const float4* wsf4 = reinterpret_cast<const float4*>(ws2);
#pragma unroll
  for (int k = 0; k < 4; ++k) {
    const int e = tid + k * 256;
    if (e < 800) {
      const int str = e / 400;
      const int i4 = e - str * 400;
      wlf4[(str * 2 + 0) * 400 + i4] = wsf4[(str * 10 + 0) * 400 + i4];
    }
  }
  __syncthreads();

  // ---- conv2: 10 stages, double-buffered weights, packed over oc pairs ----
  const int h = tid >> 7;         // ic-half
  const int grp = (tid >> 4) & 7; // 5-oc group
  const int pos = tid & 15;       // pooled output
  const int oy = (pos >> 2) * 2;
  const int ox = (pos & 3) * 2;
  v2f a01[4], a23[4];  // oc pairs (0,1) and (2,3) x 4 conv positions
  float a4[4];         // oc 4
#pragma unroll
  for (int u = 0; u < 4; ++u) {
    a01[u] = (v2f){0.f, 0.f};
    a23[u] = (v2f){0.f, 0.f};
    a4[u] = 0.f;
  }

  for (int s = 0; s < 10; ++s) {
    const int p0 = s & 1;
    float4 sv[4];
    if (s < 9) {  // early global loads for next stage
#pragma unroll
      for (int k = 0; k < 4; ++k) {
        const int e = tid + k * 256;
        if (e < 800) {
          const int str = e / 400;
          const int i4 = e - str * 400;
          sv[k] = wsf4[(str * 10 + s + 1) * 400 + i4];
        }
      }
    }
    const int ic = h * 10 + s;
    float p[6][6];
    {
      const float* ib = &h1s[ic * 144 + oy * 12 + ox];
#pragma unroll
      for (int r = 0; r < 6; ++r) {
        const float2 v0 = *reinterpret_cast<const float2*>(&ib[r * 12 + 0]);
        const float2 v1 = *reinterpret_cast<const float2*>(&ib[r * 12 + 2]);
        const float2 v2 = *reinterpret_cast<const float2*>(&ib[r * 12 + 4]);
        p[r][0] = v0.x; p[r][1] = v0.y; p[r][2] = v1.x;
        p[r][3] = v1.y; p[r][4] = v2.x; p[r][5] = v2.y;
      }
    }
    const float* wbase = &wl2[h][p0][0];
#pragma unroll
    for (int ky = 0; ky < 5; ++ky) {
#pragma unroll
      for (int kx = 0; kx < 5; ++kx) {
        const int tap = ky * 5 + kx;
        const float4 w4 =
            *reinterpret_cast<const float4*>(&wbase[tap * 64 + grp * 8]);
        const float w4b = wbase[tap * 64 + grp * 8 + 4];
        const v2f w01 = {w4.x, w4.y};
        const v2f w23 = {w4.z, w4.w};
        const float i00 = p[ky][kx];
        const float i01 = p[ky][kx + 1];
        const float i10 = p[ky + 1][kx];
        const float i11 = p[ky + 1][kx + 1];
        const v2f v00 = {i00, i00}, v01 = {i01, i01};
        const v2f v10 = {i10, i10}, v11 = {i11, i11};
        a01[0] += w01 * v00; a01[1] += w01 * v01;
        a01[2] += w01 * v10; a01[3] += w01 * v11;
        a23[0] += w23 * v00; a23[1] += w23 * v01;
        a23[2] += w23 * v10; a23[3] += w23 * v11;
        a4[0] += w4b * i00; a4[1] += w4b * i01;
        a4[2] += w4b * i10; a4[3] += w4b * i11;
      }
    }
    if (s < 9) {  // late LDS writes into other parity
#pragma unroll
      for (int k = 0; k < 4; ++k) {
        const int e = tid + k * 256;
        if (e < 800) {
          const int str = e / 400;
          const int i4 = e - str * 400;
          wlf4[(str * 2 + ((s + 1) & 1)) * 400 + i4] = sv[k];
        }
      }
    }
    __syncthreads();
  }

  // ---- merge ic-halves, pool, relu, write feats (f32 + bf16 hi/lo) ----
  const int midx = grp * 16 + pos;
  float accq[5][4];
#pragma unroll
  for (int u = 0; u < 4; ++u) {
    accq[0][u] = a01[u].x;
    accq[1][u] = a01[u].y;
    accq[2][u] = a23[u].x;
    accq[3][u] = a23[u].y;
    accq[4][u] = a4[u];
  }
  if (h == 1) {
#pragma unroll
    for (int q = 0; q < 5; ++q)
#pragma unroll
      for (int u = 0; u < 4; ++u) mg[midx][q * 4 + u] = accq[q][u];
  }
  __syncthreads();
  if (h == 0) {
#pragma unroll
    for (int q = 0; q < 5; ++q) {
      const int ch = grp * 5 + q;
      const float a0 = accq[q][0] + mg[midx][q * 4 + 0];
      const float a1 = accq[q][1] + mg[midx][q * 4 + 1];
      const float a2 = accq[q][2] + mg[midx][q * 4 + 2];
      const float a3 = accq[q][3] + mg[midx][q * 4 + 3];
      const float r0v =
          fmaxf(fmaxf(fmaxf(a0, a1), fmaxf(a2, a3)) + bl2[ch], 0.f);
      const int off = imgId * 640 + ch * 16 + pos;
      feats[off] = r0v;
      const unsigned short h0 = f2bf(r0v);
      fh[off] = h0;
      fl[off] = f2bf(r0v - bf2f(h0));
    }
  }
}

// ---- k3m: M = feats @ T^T via bf16x3 MFMA, direct-from-global -------------
__global__ __launch_bounds__(256) void k3m_gemm(
    const unsigned short* __restrict__ fh, const unsigned short* __restrict__ fl,
    const unsigned short* __restrict__ Th, const unsigned short* __restrict__ Tl,
    float* __restrict__ M) {
  const int tid = threadIdx.x;
  const int w = tid >> 6;
  const int l = tid & 63;
  const int fr = l & 15;
  const int hi = l >> 4;
  const int if0 = blockIdx.x >> 4;            // 0..31
  const int jf = (blockIdx.x & 15) * 4 + w;   // 0..63
  const int abase = (if0 * 16 + fr) * 640 + hi * 8;
  const int bbase = (jf * 16 + fr) * 640 + hi * 8;

  f32x4 acc = (f32x4){0.f, 0.f, 0.f, 0.f};
#pragma unroll
  for (int kk = 0; kk < 20; ++kk) {
    const int ko = kk * 32;
    const bf16x8 aH = *reinterpret_cast<const bf16x8*>(fh + abase + ko);
    const bf16x8 aL = *reinterpret_cast<const bf16x8*>(fl + abase + ko);
    const bf16x8 bH = *reinterpret_cast<const bf16x8*>(Th + bbase + ko);
    const bf16x8 bL = *reinterpret_cast<const bf16x8*>(Tl + bbase + ko);
    acc = __builtin_amdgcn_mfma_f32_16x16x32_bf16(aH, bH, acc, 0, 0, 0);
    acc = __builtin_amdgcn_mfma_f32_16x16x32_bf16(aL, bH, acc, 0, 0, 0);
    acc = __builtin_amdgcn_mfma_f32_16x16x32_bf16(aH, bL, acc, 0, 0, 0);
  }
#pragma unroll
  for (int r = 0; r < 4; ++r) {
    M[(if0 * 16 + hi * 4 + r) * 1024 + jf * 16 + fr] = acc[r];
  }
}

// ---- k4: partial closeness, LDS-staged swizzled j-rows --------------------
__global__ __launch_bounds__(256) void k4_mbd(const float* __restrict__ M,
                                              float* __restrict__ cp) {
  __shared__ float4 jb4[2][4][256];
  const int bid = blockIdx.x;
  const int ig = bid >> 4;
  const int jq = bid & 15;
  const int t = threadIdx.x;
  const int b = t & 63;
  const int g = t >> 6;
  const int i0 = ig * 16 + g * 4;
  const float4* Mf4 = reinterpret_cast<const float4*>(M);

  float4 mi[4][4];
#pragma unroll
  for (int u = 0; u < 4; ++u) {
#pragma unroll
    for (int q = 0; q < 4; ++q) mi[u][q] = Mf4[(i0 + u) * 256 + b * 4 + q];
  }
  const int wslot = (t >> 2) * 4 + ((t & 3) ^ ((t >> 3) & 3));
  {
#pragma unroll
    for (int k = 0; k < 4; ++k)
      jb4[0][k][wslot] = Mf4[(jq * 32 + k) * 256 + t];
  }
  __syncthreads();

  float acc[4] = {0.f, 0.f, 0.f, 0.f};
  const int xr = (b >> 1) & 3;
  for (int c = 0; c < 8; ++c) {
    float4 st[4];
    if (c < 7) {
#pragma unroll
      for (int k = 0; k < 4; ++k)
        st[k] = Mf4[(jq * 32 + (c + 1) * 4 + k) * 256 + t];
    }
    const int cbuf = c & 1;
#pragma unroll
    for (int jj = 0; jj < 4; ++jj) {
      const float4* rowp = jb4[cbuf][jj];
      float4 mj[4];
#pragma unroll
      for (int q = 0; q < 4; ++q) mj[q] = rowp[b * 4 + (q ^ xr)];
#pragma unroll
      for (int u = 0; u < 4; ++u) {
        float dist =
            fabsf(mi[u][0].x - mj[0].x) + fabsf(mi[u][0].y - mj[0].y) +
            fabsf(mi[u][0].z - mj[0].z) + fabsf(mi[u][0].w - mj[0].w) +
            fabsf(mi[u][1].x - mj[1].x) + fabsf(mi[u][1].y - mj[1].y) +
            fabsf(mi[u][1].z - mj[1].z) + fabsf(mi[u][1].w - mj[1].w) +
            fabsf(mi[u][2].x - mj[2].x) + fabsf(mi[u][2].y - mj[2].y) +
            fabsf(mi[u][2].z - mj[2].z) + fabsf(mi[u][2].w - mj[2].w) +
            fabsf(mi[u][3].x - mj[3].x) + fabsf(mi[u][3].y - mj[3].y) +
            fabsf(mi[u][3].z - mj[3].z) + fabsf(mi[u][3].w - mj[3].w);
        acc[u] += __expf(-dist);
      }
    }
    if (c < 7) {
#pragma unroll
      for (int k = 0; k < 4; ++k) jb4[(c + 1) & 1][k][wslot] = st[k];
    }
    __syncthreads();
  }
#pragma unroll
  for (int u = 0; u < 4; ++u)
    cp[(jq * 512 + i0 + u) * 64 + b] = acc[u];
}

// ---- k5: head -------------------------------------------------------------
__global__ __launch_bounds__(256) void k5_head(
    const float* __restrict__ feats, const float* __restrict__ cp,
    const float* __restrict__ w1, const float* __restrict__ b1,
    const float* __restrict__ w2, const float* __restrict__ b2,
    float* __restrict__ out) {
  __shared__ __align__(16) float v[704];
  __shared__ float hb[100];
  const int i = blockIdx.x;
  const int tid = threadIdx.x;
  float4* v4 = reinterpret_cast<float4*>(v);
  if (tid < 160)
    v4[tid] = reinterpret_cast<const float4*>(feats + i * 640)[tid];
  if (tid >= 192) {
    const int bb = tid - 192;
    float s = 0.f;
#pragma unroll
    for (int q = 0; q < 16; ++q) s += cp[(q * 512 + i) * 64 + bb];
    v[640 + bb] = s;
  }
  __syncthreads();
  const int wave = tid >> 6;
  const int lane = tid & 63;
  for (int r = wave; r < 100; r += 4) {
    const float4* wr = reinterpret_cast<const float4*>(w1 + r * 704);
    const float4 wa = wr[lane];
    const float4 wb = wr[lane + 64];
    const float4 va = v4[lane];
    const float4 vb = v4[lane + 64];
    float s = wa.x * va.x + wa.y * va.y + wa.z * va.z + wa.w * va.w +
              wb.x * vb.x + wb.y * vb.y + wb.z * vb.z + wb.w * vb.w;
    if (lane < 48) {
      const float4 wc = wr[lane + 128];
      const float4 vc = v4[lane + 128];
      s += wc.x * vc.x + wc.y * vc.y + wc.z * vc.z + wc.w * vc.w;
    }
#pragma unroll
    for (int off = 32; off; off >>= 1) s += __shfl_xor(s, off);
    if (lane == 0) hb[r] = fmaxf(s + b1[r], 0.f) * w2[r];
  }
  __syncthreads();
  if (tid < 64) {
    float s = hb[tid] + ((tid < 36) ? hb[tid + 64] : 0.f);
#pragma unroll
    for (int off = 32; off; off >>= 1) s += __shfl_xor(s, off);
    if (tid == 0) out[i] = 1.f / (1.f + __expf(-(s + b2[0])));
  }
}

extern "C" void kernel_launch(void* const* d_in, const int* in_sizes, int n_in,
                              void* d_out, int out_size, void* d_ws,
                              size_t ws_size, hipStream_t stream) {
  const float* x   = (const float*)d_in[0];
  const float* c1w = (const float*)d_in[1];
  const float* c1b = (const float*)d_in[2];
  const float* c2w = (const float*)d_in[3];
  const float* c2b = (const float*)d_in[4];
  const float* T   = (const float*)d_in[5];
  const float* f1w = (const float*)d_in[6];
  const float* f1b = (const float*)d_in[7];
  const float* f2w = (const float*)d_in[8];
  const float* f2b = (const float*)d_in[9];
  float* out = (float*)d_out;

  float* feats = (float*)d_ws;                    // 327680 f
  float* M     = feats + 327680;                  // 524288 f
  float* cp    = M + 524288;                      // 524288 f
  float* ws2   = cp + 524288;                     // 32000 f
  unsigned short* fh = (unsigned short*)(ws2 + 32000);  // 327680 u16
  unsigned short* fl = fh + 327680;
  unsigned short* Th = fl + 327680;               // 655360 u16
  unsigned short* Tl = Th + 655360;
  // total ~9.6 MB

  kP_prep<<<2560, 256, 0, stream>>>(c2w, T, ws2, Th, Tl);
  kC_conv<<<512, 256, 0, stream>>>(x, c1w, c1b, ws2, c2b, feats, fh, fl);
  k3m_gemm<<<512, 256, 0, stream>>>(fh, fl, Th, Tl, M);
  k4_mbd<<<512, 256, 0, stream>>>(M, cp);
  k5_head<<<512, 256, 0, stream>>>(feats, cp, f1w, f1b, f2w, f2b, out);
}